// Round 1
// baseline (479.577 us; speedup 1.0000x reference)
//
#include <hip/hip_runtime.h>
#include <math.h>

typedef __attribute__((ext_vector_type(8))) short bf16x8;
typedef __attribute__((ext_vector_type(4))) float f32x4;

#define HID 2048
#define SEQ 2048
#define NH  16
#define DH  128
#define QK_SCALE 0.02209708691207961f  // 1/sqrt(2048)

__device__ __forceinline__ ushort f2bf(float f) {
  union { float f; unsigned u; } v; v.f = f;
  unsigned r = v.u + 0x7fffu + ((v.u >> 16) & 1u);
  return (ushort)(r >> 16);
}

// ---------- transpose fp32 [2048][2048] -> bf16 [2048][2048] (Wt[n][k] = W[k][n]) ----------
__global__ __launch_bounds__(256) void k_transpose(const float* __restrict__ W,
                                                   ushort* __restrict__ Wt) {
  __shared__ float t[32][33];
  int n0 = blockIdx.x * 32, k0 = blockIdx.y * 32;
  int tx = threadIdx.x, ty = threadIdx.y;
  for (int i = ty; i < 32; i += 8)
    t[i][tx] = W[(size_t)(k0 + i) * HID + n0 + tx];
  __syncthreads();
  for (int i = ty; i < 32; i += 8)
    Wt[(size_t)(n0 + i) * HID + k0 + tx] = f2bf(t[tx][i]);
}

// ---------- RMSNorm: x fp32 [4096][2048] -> xn bf16 ----------
__global__ __launch_bounds__(256) void k_rmsnorm(const float* __restrict__ x,
                                                 const float* __restrict__ w,
                                                 ushort* __restrict__ xn) {
  int row = blockIdx.x;
  const float* xr = x + (size_t)row * HID;
  int base = threadIdx.x * 8;
  float4 a = *(const float4*)(xr + base);
  float4 c = *(const float4*)(xr + base + 4);
  float ss = a.x*a.x + a.y*a.y + a.z*a.z + a.w*a.w
           + c.x*c.x + c.y*c.y + c.z*c.z + c.w*c.w;
  #pragma unroll
  for (int off = 32; off > 0; off >>= 1) ss += __shfl_xor(ss, off);
  __shared__ float red[4];
  if ((threadIdx.x & 63) == 0) red[threadIdx.x >> 6] = ss;
  __syncthreads();
  float tot = red[0] + red[1] + red[2] + red[3];
  float sc = rsqrtf(tot * (1.0f / HID) + 1e-5f);
  float4 wa = *(const float4*)(w + base);
  float4 wc = *(const float4*)(w + base + 4);
  ushort h[8];
  h[0] = f2bf(a.x * sc * wa.x); h[1] = f2bf(a.y * sc * wa.y);
  h[2] = f2bf(a.z * sc * wa.z); h[3] = f2bf(a.w * sc * wa.w);
  h[4] = f2bf(c.x * sc * wc.x); h[5] = f2bf(c.y * sc * wc.y);
  h[6] = f2bf(c.z * sc * wc.z); h[7] = f2bf(c.w * sc * wc.w);
  int4 pk;
  pk.x = h[0] | ((int)h[1] << 16);
  pk.y = h[2] | ((int)h[3] << 16);
  pk.z = h[4] | ((int)h[5] << 16);
  pk.w = h[6] | ((int)h[7] << 16);
  *(int4*)&xn[(size_t)row * HID + base] = pk;
}

// ---------- GEMM: C[M][N] = A[M][K](bf16) * Bt[N][K](bf16)^T ----------
// MODE 0: qkv projection, N=6144. cols<4096 -> bf16 into qk[4096][4096];
//         cols>=4096 (V) -> transposed bf16 store vt[(b*16+h)*128+d][2048] = V[b,s,h,d]
// MODE 1: output projection, N=2048. fp32 out + residual.
template <int MODE>
__global__ __launch_bounds__(256) void k_gemm(const ushort* __restrict__ A,
                                              const ushort* __restrict__ Bt,
                                              ushort* __restrict__ obf,
                                              ushort* __restrict__ vt,
                                              float* __restrict__ ofl,
                                              const float* __restrict__ resid,
                                              int K) {
  __shared__ ushort sA[128][72];  // +8 bf16 pad: 2-way bank conflict only (free)
  __shared__ ushort sB[128][72];
  int tid = threadIdx.x;
  int lane = tid & 63, wave = tid >> 6;
  int wr = wave >> 1, wc = wave & 1;  // 2x2 waves, 64x64 each
  int bm = blockIdx.y, bn = blockIdx.x;
  f32x4 zero = {0.f, 0.f, 0.f, 0.f};
  f32x4 acc[4][4];
  #pragma unroll
  for (int i = 0; i < 4; ++i)
    #pragma unroll
    for (int j = 0; j < 4; ++j) acc[i][j] = zero;

  for (int k0 = 0; k0 < K; k0 += 64) {
    #pragma unroll
    for (int c = 0; c < 4; ++c) {        // 1024 16B-chunks per matrix, 4/thread
      int id = c * 256 + tid;
      int r = id >> 3;
      int kc = (id & 7) << 3;
      *(int4*)&sA[r][kc] = *(const int4*)&A[(size_t)(bm * 128 + r) * K + k0 + kc];
      *(int4*)&sB[r][kc] = *(const int4*)&Bt[(size_t)(bn * 128 + r) * K + k0 + kc];
    }
    __syncthreads();
    #pragma unroll
    for (int kk = 0; kk < 2; ++kk) {
      int krow = kk * 32 + (lane >> 4) * 8;
      bf16x8 aF[4], bF[4];
      #pragma unroll
      for (int i = 0; i < 4; ++i)
        aF[i] = *(const bf16x8*)&sA[wr * 64 + i * 16 + (lane & 15)][krow];
      #pragma unroll
      for (int j = 0; j < 4; ++j)
        bF[j] = *(const bf16x8*)&sB[wc * 64 + j * 16 + (lane & 15)][krow];
      #pragma unroll
      for (int i = 0; i < 4; ++i)
        #pragma unroll
        for (int j = 0; j < 4; ++j)
          acc[i][j] = __builtin_amdgcn_mfma_f32_16x16x32_bf16(aF[i], bF[j], acc[i][j], 0, 0, 0);
    }
    __syncthreads();
  }

  // C/D layout: col = lane&15, row = (lane>>4)*4 + r  [m89-verified]
  int rbase = bm * 128 + wr * 64 + (lane >> 4) * 4;
  int cbase = bn * 128 + wc * 64 + (lane & 15);
  #pragma unroll
  for (int i = 0; i < 4; ++i) {
    #pragma unroll
    for (int j = 0; j < 4; ++j) {
      int col = cbase + j * 16;
      #pragma unroll
      for (int r = 0; r < 4; ++r) {
        int row = rbase + i * 16 + r;
        float v = acc[i][j][r];
        if (MODE == 0) {
          ushort hv = f2bf(v);
          if (col < 4096) {
            obf[(size_t)row * 4096 + col] = hv;
          } else {
            int nv = col - 4096;
            int h = nv >> 7, d = nv & 127;
            int b = row >> 11, s = row & 2047;
            vt[(size_t)((b * NH + h) * DH + d) * SEQ + s] = hv;
          }
        } else {
          ofl[(size_t)row * HID + col] = v + resid[(size_t)row * HID + col];
        }
      }
    }
  }
}

// ---------- flash attention: qk[4096][4096] (q cols 0..2047, k cols 2048..4095), vt[b,h,d][s] ----------
__global__ __launch_bounds__(256) void k_attn(const ushort* __restrict__ qk,
                                              const ushort* __restrict__ vt,
                                              ushort* __restrict__ aout) {
  __shared__ ushort sK[32][136];    // K tile [t][d], +8 pad
  __shared__ ushort sVt[128][40];   // V^T tile [d][t], +8 pad
  __shared__ ushort sP[4][16][40];  // per-wave P relayout buffer
  int tid = threadIdx.x, lane = tid & 63, wave = tid >> 6;
  int qt = blockIdx.x, bh = blockIdx.y;
  int b = bh >> 4, h = bh & 15;
  int q0 = qt * 64 + wave * 16;  // this wave's 16 q rows
  int koff = (lane >> 4) * 8;

  bf16x8 qF[4];
  {
    const ushort* qrow = qk + (size_t)(b * SEQ + q0 + (lane & 15)) * 4096 + h * DH;
    #pragma unroll
    for (int kk = 0; kk < 4; ++kk) qF[kk] = *(const bf16x8*)&qrow[kk * 32 + koff];
  }

  f32x4 zero = {0.f, 0.f, 0.f, 0.f};
  f32x4 acc[8];
  #pragma unroll
  for (int i = 0; i < 8; ++i) acc[i] = zero;
  float m_r[4] = {-1e30f, -1e30f, -1e30f, -1e30f};
  float l_r[4] = {0.f, 0.f, 0.f, 0.f};

  int ntiles = qt * 2 + 2;
  for (int t = 0; t < ntiles; ++t) {
    int t0 = t * 32;
    #pragma unroll
    for (int c = 0; c < 2; ++c) {
      int id = c * 256 + tid;
      {  // K tile: 32 rows x 128 d
        int r = id >> 4;
        int dc = (id & 15) << 3;
        *(int4*)&sK[r][dc] =
            *(const int4*)&qk[(size_t)(b * SEQ + t0 + r) * 4096 + 2048 + h * DH + dc];
      }
      {  // Vt tile: 128 rows (d) x 32 t
        int dr = id >> 2;
        int tc = (id & 3) << 3;
        *(int4*)&sVt[dr][tc] = *(const int4*)&vt[(size_t)(bh * DH + dr) * SEQ + t0 + tc];
      }
    }
    __syncthreads();

    // S = Q K^T  (two 16-col halves)
    f32x4 S0 = zero, S1 = zero;
    #pragma unroll
    for (int kk = 0; kk < 4; ++kk) {
      int krow = kk * 32 + koff;
      bf16x8 k0f = *(const bf16x8*)&sK[lane & 15][krow];
      bf16x8 k1f = *(const bf16x8*)&sK[16 + (lane & 15)][krow];
      S0 = __builtin_amdgcn_mfma_f32_16x16x32_bf16(qF[kk], k0f, S0, 0, 0, 0);
      S1 = __builtin_amdgcn_mfma_f32_16x16x32_bf16(qF[kk], k1f, S1, 0, 0, 0);
    }

    // online softmax; row s lives in 16-lane group (lane>>4), reg r
    #pragma unroll
    for (int r = 0; r < 4; ++r) {
      int sg = q0 + (lane >> 4) * 4 + r;
      int tg = t0 + (lane & 15);
      float v0 = (tg <= sg) ? S0[r] * QK_SCALE : -INFINITY;
      float v1 = (tg + 16 <= sg) ? S1[r] * QK_SCALE : -INFINITY;
      float mx = fmaxf(v0, v1);
      #pragma unroll
      for (int off = 1; off < 16; off <<= 1) mx = fmaxf(mx, __shfl_xor(mx, off));
      float mnew = fmaxf(m_r[r], mx);          // finite init -1e30 avoids inf-inf NaN
      float alpha = __expf(m_r[r] - mnew);
      float p0 = __expf(v0 - mnew);
      float p1 = __expf(v1 - mnew);
      float rs = p0 + p1;
      #pragma unroll
      for (int off = 1; off < 16; off <<= 1) rs += __shfl_xor(rs, off);
      l_r[r] = l_r[r] * alpha + rs;
      m_r[r] = mnew;
      #pragma unroll
      for (int d8 = 0; d8 < 8; ++d8) acc[d8][r] *= alpha;
      sP[wave][(lane >> 4) * 4 + r][lane & 15] = f2bf(p0);
      sP[wave][(lane >> 4) * 4 + r][16 + (lane & 15)] = f2bf(p1);
    }
    __syncthreads();

    // O += P V : A-frag from sP, B-frag from sVt
    bf16x8 pF = *(const bf16x8*)&sP[wave][lane & 15][koff];
    #pragma unroll
    for (int d8 = 0; d8 < 8; ++d8) {
      bf16x8 vF = *(const bf16x8*)&sVt[d8 * 16 + (lane & 15)][koff];
      acc[d8] = __builtin_amdgcn_mfma_f32_16x16x32_bf16(pF, vF, acc[d8], 0, 0, 0);
    }
    __syncthreads();
  }

  #pragma unroll
  for (int d8 = 0; d8 < 8; ++d8) {
    #pragma unroll
    for (int r = 0; r < 4; ++r) {
      int sg = q0 + (lane >> 4) * 4 + r;
      int dg = h * DH + d8 * 16 + (lane & 15);
      aout[(size_t)(b * SEQ + sg) * HID + dg] = f2bf(acc[d8][r] / l_r[r]);
    }
  }
}

extern "C" void kernel_launch(void* const* d_in, const int* in_sizes, int n_in,
                              void* d_out, int out_size, void* d_ws, size_t ws_size,
                              hipStream_t stream) {
  const float* x     = (const float*)d_in[0];
  const float* rms_w = (const float*)d_in[1];
  const float* Wq    = (const float*)d_in[2];
  const float* Wk    = (const float*)d_in[3];
  const float* Wv    = (const float*)d_in[4];
  const float* Wo    = (const float*)d_in[5];
  float* out = (float*)d_out;

  // workspace layout (bf16 buffers), total ~112 MB
  char* ws = (char*)d_ws;
  ushort* WqkvT = (ushort*)ws; ws += (size_t)6144 * 2048 * 2;  // [6144][2048]
  ushort* WoT   = (ushort*)ws; ws += (size_t)2048 * 2048 * 2;  // [2048][2048]
  ushort* xn    = (ushort*)ws; ws += (size_t)4096 * 2048 * 2;  // [4096][2048]
  ushort* qkbuf = (ushort*)ws; ws += (size_t)4096 * 4096 * 2;  // [4096][4096]
  ushort* vt    = (ushort*)ws; ws += (size_t)4096 * 2048 * 2;  // [(b,h,d)][2048]
  ushort* aout  = (ushort*)ws; ws += (size_t)4096 * 2048 * 2;  // [4096][2048]

  dim3 tb(32, 8), tg(64, 64);
  k_transpose<<<tg, tb, 0, stream>>>(Wq, WqkvT);
  k_transpose<<<tg, tb, 0, stream>>>(Wk, WqkvT + (size_t)2048 * 2048);
  k_transpose<<<tg, tb, 0, stream>>>(Wv, WqkvT + (size_t)4096 * 2048);
  k_transpose<<<tg, tb, 0, stream>>>(Wo, WoT);

  k_rmsnorm<<<4096, 256, 0, stream>>>(x, rms_w, xn);

  // QKV: M=4096, N=6144, K=2048
  k_gemm<0><<<dim3(48, 32), 256, 0, stream>>>(xn, WqkvT, qkbuf, vt, nullptr, nullptr, 2048);

  // attention: 32 q-tiles x 32 (b,h)
  k_attn<<<dim3(32, 32), 256, 0, stream>>>(qkbuf, vt, aout);

  // out = attn @ Wo + x : M=4096, N=2048, K=2048
  k_gemm<1><<<dim3(16, 32), 256, 0, stream>>>(aout, WoT, nullptr, nullptr, out, x, 2048);
}

// Round 2
// 301.950 us; speedup vs baseline: 1.5883x; 1.5883x over previous
//
#include <hip/hip_runtime.h>
#include <math.h>

typedef __attribute__((ext_vector_type(8))) short bf16x8;
typedef __attribute__((ext_vector_type(4))) float f32x4;
typedef __attribute__((ext_vector_type(16))) float f32x16;

#define HID 2048
#define SEQ 2048
#define NH  16
#define DH  128
#define QK_SCALE 0.02209708691207961f  // 1/sqrt(2048)

__device__ __forceinline__ ushort f2bf(float f) {
  union { float f; unsigned u; } v; v.f = f;
  unsigned r = v.u + 0x7fffu + ((v.u >> 16) & 1u);
  return (ushort)(r >> 16);
}

// async global->LDS, 16B per lane. lds ptr must be wave-uniform; HW adds lane*16.
__device__ __forceinline__ void gload16(const ushort* g, ushort* l) {
  __builtin_amdgcn_global_load_lds((const __attribute__((address_space(1))) void*)g,
                                   (__attribute__((address_space(3))) void*)l,
                                   16, 0, 0);
}

// ---------- transpose fp32 [2048][2048] -> bf16 [2048][2048] (Wt[n][k] = W[k][n]) ----------
__global__ __launch_bounds__(256) void k_transpose(const float* __restrict__ W,
                                                   ushort* __restrict__ Wt) {
  __shared__ float t[32][33];
  int n0 = blockIdx.x * 32, k0 = blockIdx.y * 32;
  int tx = threadIdx.x, ty = threadIdx.y;
  for (int i = ty; i < 32; i += 8)
    t[i][tx] = W[(size_t)(k0 + i) * HID + n0 + tx];
  __syncthreads();
  for (int i = ty; i < 32; i += 8)
    Wt[(size_t)(n0 + i) * HID + k0 + tx] = f2bf(t[tx][i]);
}

// ---------- RMSNorm: x fp32 [4096][2048] -> xn bf16 ----------
__global__ __launch_bounds__(256) void k_rmsnorm(const float* __restrict__ x,
                                                 const float* __restrict__ w,
                                                 ushort* __restrict__ xn) {
  int row = blockIdx.x;
  const float* xr = x + (size_t)row * HID;
  int base = threadIdx.x * 8;
  float4 a = *(const float4*)(xr + base);
  float4 c = *(const float4*)(xr + base + 4);
  float ss = a.x*a.x + a.y*a.y + a.z*a.z + a.w*a.w
           + c.x*c.x + c.y*c.y + c.z*c.z + c.w*c.w;
  #pragma unroll
  for (int off = 32; off > 0; off >>= 1) ss += __shfl_xor(ss, off);
  __shared__ float red[4];
  if ((threadIdx.x & 63) == 0) red[threadIdx.x >> 6] = ss;
  __syncthreads();
  float tot = red[0] + red[1] + red[2] + red[3];
  float sc = rsqrtf(tot * (1.0f / HID) + 1e-5f);
  float4 wa = *(const float4*)(w + base);
  float4 wc = *(const float4*)(w + base + 4);
  ushort h[8];
  h[0] = f2bf(a.x * sc * wa.x); h[1] = f2bf(a.y * sc * wa.y);
  h[2] = f2bf(a.z * sc * wa.z); h[3] = f2bf(a.w * sc * wa.w);
  h[4] = f2bf(c.x * sc * wc.x); h[5] = f2bf(c.y * sc * wc.y);
  h[6] = f2bf(c.z * sc * wc.z); h[7] = f2bf(c.w * sc * wc.w);
  int4 pk;
  pk.x = h[0] | ((int)h[1] << 16);
  pk.y = h[2] | ((int)h[3] << 16);
  pk.z = h[4] | ((int)h[5] << 16);
  pk.w = h[6] | ((int)h[7] << 16);
  *(int4*)&xn[(size_t)row * HID + base] = pk;
}

// ---------- GEMM (m97 structure): C[M][N] = A[M][K](bf16) * Bt[N][K](bf16)^T ----------
// LDS linear [128][64] per matrix, staged via global_load_lds(16B) with
// both-sides XOR chunk swizzle (chunk ^= row&7) for conflict-free ds_read_b128.
// MODE 0: qkv projection, N=6144. cols<4096 -> bf16 into qk[4096][4096];
//         cols>=4096 (V) -> transposed bf16 store vt[(b*16+h)*128+d][2048]
// MODE 1: output projection, N=2048. fp32 out + residual.
template <int MODE>
__global__ __launch_bounds__(256) void k_gemm(const ushort* __restrict__ A,
                                              const ushort* __restrict__ Bt,
                                              ushort* __restrict__ obf,
                                              ushort* __restrict__ vt,
                                              float* __restrict__ ofl,
                                              const float* __restrict__ resid,
                                              int K) {
  __shared__ ushort sA[128 * 64];
  __shared__ ushort sB[128 * 64];
  const int tid = threadIdx.x;
  const int lane = tid & 63, w = tid >> 6;
  const int wr = w >> 1, wc = w & 1;  // 2x2 waves, 64x64 each
  const int bm = blockIdx.y, bn = blockIdx.x;
  const int g = lane >> 4, l15 = lane & 15;
  f32x4 zero = {0.f, 0.f, 0.f, 0.f};
  f32x4 acc[4][4];
  #pragma unroll
  for (int i = 0; i < 4; ++i)
    #pragma unroll
    for (int j = 0; j < 4; ++j) acc[i][j] = zero;

  for (int k0 = 0; k0 < K; k0 += 64) {
    // stage: 1024 16B-chunks per matrix; chunk id -> row=id>>3, phys chunk=id&7;
    // value stored at phys chunk cp is logical chunk cp^(row&7) (XOR involution)
    #pragma unroll
    for (int c = 0; c < 4; ++c) {
      int id = (w * 4 + c) * 64 + lane;
      int r = id >> 3, ck = id & 7;
      int ke = k0 + ((ck ^ (r & 7)) * 8);
      gload16(&A[(size_t)(bm * 128 + r) * K + ke], ((ushort*)sA) + (size_t)(w * 4 + c) * 512);
      gload16(&Bt[(size_t)(bn * 128 + r) * K + ke], ((ushort*)sB) + (size_t)(w * 4 + c) * 512);
    }
    __syncthreads();
    #pragma unroll
    for (int kk = 0; kk < 2; ++kk) {
      bf16x8 aF[4], bF[4];
      #pragma unroll
      for (int i = 0; i < 4; ++i) {
        int row = wr * 64 + i * 16 + l15;   // row&7 == lane&7
        int cp = (kk * 4 + g) ^ (lane & 7);
        aF[i] = *(const bf16x8*)&sA[row * 64 + cp * 8];
      }
      #pragma unroll
      for (int j = 0; j < 4; ++j) {
        int row = wc * 64 + j * 16 + l15;
        int cp = (kk * 4 + g) ^ (lane & 7);
        bF[j] = *(const bf16x8*)&sB[row * 64 + cp * 8];
      }
      #pragma unroll
      for (int i = 0; i < 4; ++i)
        #pragma unroll
        for (int j = 0; j < 4; ++j)
          acc[i][j] = __builtin_amdgcn_mfma_f32_16x16x32_bf16(aF[i], bF[j], acc[i][j], 0, 0, 0);
    }
    __syncthreads();
  }

  // C/D layout: col = lane&15, row = (lane>>4)*4 + r
  int rbase = bm * 128 + wr * 64 + (lane >> 4) * 4;
  int cbase = bn * 128 + wc * 64 + l15;
  #pragma unroll
  for (int i = 0; i < 4; ++i) {
    #pragma unroll
    for (int j = 0; j < 4; ++j) {
      int col = cbase + j * 16;
      #pragma unroll
      for (int r = 0; r < 4; ++r) {
        int row = rbase + i * 16 + r;
        float v = acc[i][j][r];
        if (MODE == 0) {
          ushort hv = f2bf(v);
          if (col < 4096) {
            obf[(size_t)row * 4096 + col] = hv;
          } else {
            int nv = col - 4096;
            int h = nv >> 7, d = nv & 127;
            int b = row >> 11, s = row & 2047;
            vt[(size_t)((b * NH + h) * DH + d) * SEQ + s] = hv;
          }
        } else {
          ofl[(size_t)row * HID + col] = v + resid[(size_t)row * HID + col];
        }
      }
    }
  }
}

// ---------- flash attention v2: 4 waves x QBLK=32, KVBLK=64, 32x32x16 MFMA ----------
// Swapped QK^T (mfma(K,Q)) -> lane owns q = lane&31 P-row; in-register softmax;
// defer-max (THR=8); P->A-frag via bf16-pack + shfl_xor(32) half exchange.
// sK[64][128], sV[128][64] staged via global_load_lds with chunk^(row&7) swizzle.
__global__ __launch_bounds__(256, 2) void k_attn2(const ushort* __restrict__ qk,
                                                  const ushort* __restrict__ vt,
                                                  ushort* __restrict__ aout) {
  __shared__ ushort sK[64 * 128];
  __shared__ ushort sV[128 * 64];
  const int tid = threadIdx.x;
  const int lane = tid & 63, w = tid >> 6;
  const int h2 = lane >> 5;          // half of wave
  const int l31 = lane & 31;
  // block decode: bid&7 -> XCD slot; all 16 q-blocks of a (b,h) share slot; big qblk first
  const int bid = blockIdx.x;
  const int t = bid >> 3;
  const int bh = (bid & 7) + 8 * (t >> 4);
  const int qblk = 15 - (t & 15);
  const int b = bh >> 4, hh = bh & 15;
  const int q0w = qblk * 128 + w * 32;   // this wave's 32 q rows

  // Q fragments in registers (B-operand of swapped QK): q = q0w + l31
  bf16x8 qf[8];
  {
    const ushort* qbase = qk + (size_t)(b * SEQ + q0w + l31) * 4096 + hh * DH;
    #pragma unroll
    for (int kk = 0; kk < 8; ++kk) qf[kk] = *(const bf16x8*)&qbase[kk * 16 + h2 * 8];
  }

  f32x16 accO[4];
  #pragma unroll
  for (int i = 0; i < 4; ++i)
    #pragma unroll
    for (int r = 0; r < 16; ++r) accO[i][r] = 0.f;
  float m_r = -1e30f, l_r = 0.f;

  const int ntile = 2 * qblk + 2;
  for (int tt = 0; tt < ntile; ++tt) {
    const int t0 = tt * 64;
    // ---- stage K[64][128] and V^T[128][64]; linear dest, pre-swizzled source
    #pragma unroll
    for (int c = 0; c < 4; ++c) {
      int id = (w * 4 + c) * 64 + lane;
      int kr = id >> 4, ck = id & 15;   // sK: 256B rows, 16 chunks
      gload16(qk + (size_t)(b * SEQ + t0 + kr) * 4096 + 2048 + hh * DH + ((ck ^ (kr & 7)) * 8),
              ((ushort*)sK) + (size_t)(w * 4 + c) * 512);
      int dr = id >> 3, cv = id & 7;    // sV: 128B rows, 8 chunks
      gload16(vt + (size_t)(bh * DH + dr) * SEQ + t0 + ((cv ^ (dr & 7)) * 8),
              ((ushort*)sV) + (size_t)(w * 4 + c) * 512);
    }
    __syncthreads();

    if (t0 <= q0w + 31) {  // wave-uniform; inactive waves only keep barriers
      // ---- S^T = K * Q^T : accS[kt] rows k, cols q
      f32x16 accS[2];
      #pragma unroll
      for (int i = 0; i < 2; ++i)
        #pragma unroll
        for (int r = 0; r < 16; ++r) accS[i][r] = 0.f;
      #pragma unroll
      for (int kt = 0; kt < 2; ++kt) {
        const int row = kt * 32 + l31;   // row&7 == lane&7
        #pragma unroll
        for (int kk = 0; kk < 8; ++kk) {
          const int cp = (kk * 2 + h2) ^ (lane & 7);
          bf16x8 kf = *(const bf16x8*)&sK[row * 128 + cp * 8];
          accS[kt] = __builtin_amdgcn_mfma_f32_32x32x16_bf16(kf, qf[kk], accS[kt], 0, 0, 0);
        }
      }
      // ---- in-register softmax; lane owns q = q0w + l31;
      // element r of accS[kt] is k = t0 + kt*32 + (r&3) + 8*(r>>2) + 4*h2
      const int qa = q0w + l31;
      float pmax = -INFINITY;
      if (t0 + 63 <= q0w) {  // interior tile: no mask
        #pragma unroll
        for (int kt = 0; kt < 2; ++kt)
          #pragma unroll
          for (int r = 0; r < 16; ++r) {
            float s = accS[kt][r] * QK_SCALE;
            accS[kt][r] = s;
            pmax = fmaxf(pmax, s);
          }
      } else {
        #pragma unroll
        for (int kt = 0; kt < 2; ++kt)
          #pragma unroll
          for (int r = 0; r < 16; ++r) {
            int ka = t0 + kt * 32 + (r & 3) + 8 * (r >> 2) + 4 * h2;
            float s = (ka <= qa) ? accS[kt][r] * QK_SCALE : -INFINITY;
            accS[kt][r] = s;
            pmax = fmaxf(pmax, s);
          }
      }
      pmax = fmaxf(pmax, __shfl_xor(pmax, 32));
      if (__any(pmax > m_r + 8.f)) {   // defer-max: fires on first tile only in practice
        float mn = fmaxf(m_r, pmax);
        float al = __expf(m_r - mn);
        m_r = mn;
        l_r *= al;
        #pragma unroll
        for (int r = 0; r < 16; ++r) {
          float ar = __shfl(al, (r & 3) + 8 * (r >> 2) + 4 * h2);
          #pragma unroll
          for (int ds = 0; ds < 4; ++ds) accO[ds][r] *= ar;
        }
      }
      float rs = 0.f;
      #pragma unroll
      for (int kt = 0; kt < 2; ++kt)
        #pragma unroll
        for (int r = 0; r < 16; ++r) {
          float p = __expf(accS[kt][r] - m_r);
          rs += p;
          accS[kt][r] = p;
        }
      rs += __shfl_xor(rs, 32);
      l_r += rs;
      // pack P to bf16 dword pairs: W[kt][bq][w2] = k-in-32 {8bq+4h2+2w2, +1}
      uint W[2][4][2];
      #pragma unroll
      for (int kt = 0; kt < 2; ++kt)
        #pragma unroll
        for (int bq = 0; bq < 4; ++bq)
          #pragma unroll
          for (int w2 = 0; w2 < 2; ++w2) {
            uint u0 = __float_as_uint(accS[kt][bq * 4 + w2 * 2]);
            uint u1 = __float_as_uint(accS[kt][bq * 4 + w2 * 2 + 1]);
            W[kt][bq][w2] = (u0 >> 16) | (u1 & 0xffff0000u);
          }
      // ---- O += P V : pfrag(kc) covers k = kc*16 + h2*8 + 0..7
      #pragma unroll
      for (int kc = 0; kc < 4; ++kc) {
        const int kt = kc >> 1, pq = kc & 1;
        uint X0 = W[kt][2 * pq][0],     X1 = W[kt][2 * pq][1];
        uint Y0 = W[kt][2 * pq + 1][0], Y1 = W[kt][2 * pq + 1][1];
        uint sx0 = (uint)__shfl_xor((int)X0, 32);
        uint sx1 = (uint)__shfl_xor((int)X1, 32);
        uint sy0 = (uint)__shfl_xor((int)Y0, 32);
        uint sy1 = (uint)__shfl_xor((int)Y1, 32);
        union { uint u[4]; bf16x8 v; } pu;
        pu.u[0] = h2 ? sy0 : X0;   // quad (b', hh=0)
        pu.u[1] = h2 ? sy1 : X1;
        pu.u[2] = h2 ? Y0 : sx0;   // quad (b', hh=1)
        pu.u[3] = h2 ? Y1 : sx1;
        #pragma unroll
        for (int ds = 0; ds < 4; ++ds) {
          const int dr = ds * 32 + l31;             // row&7 == lane&7
          const int cp = (kc * 2 + h2) ^ (lane & 7);
          bf16x8 vf = *(const bf16x8*)&sV[dr * 64 + cp * 8];
          accO[ds] = __builtin_amdgcn_mfma_f32_32x32x16_bf16(pu.v, vf, accO[ds], 0, 0, 0);
        }
      }
    }
    __syncthreads();
  }

  // epilogue: O row q = (r&3)+8*(r>>2)+4*h2, col d = ds*32 + l31
  float linv = 1.f / l_r;
  #pragma unroll
  for (int r = 0; r < 16; ++r) {
    int qrel = (r & 3) + 8 * (r >> 2) + 4 * h2;
    float li = __shfl(linv, qrel);
    #pragma unroll
    for (int ds = 0; ds < 4; ++ds) {
      aout[(size_t)(b * SEQ + q0w + qrel) * HID + hh * DH + ds * 32 + l31] =
          f2bf(accO[ds][r] * li);
    }
  }
}

extern "C" void kernel_launch(void* const* d_in, const int* in_sizes, int n_in,
                              void* d_out, int out_size, void* d_ws, size_t ws_size,
                              hipStream_t stream) {
  const float* x     = (const float*)d_in[0];
  const float* rms_w = (const float*)d_in[1];
  const float* Wq    = (const float*)d_in[2];
  const float* Wk    = (const float*)d_in[3];
  const float* Wv    = (const float*)d_in[4];
  const float* Wo    = (const float*)d_in[5];
  float* out = (float*)d_out;

  // workspace layout (bf16 buffers), total ~112 MB
  char* ws = (char*)d_ws;
  ushort* WqkvT = (ushort*)ws; ws += (size_t)6144 * 2048 * 2;  // [6144][2048]
  ushort* WoT   = (ushort*)ws; ws += (size_t)2048 * 2048 * 2;  // [2048][2048]
  ushort* xn    = (ushort*)ws; ws += (size_t)4096 * 2048 * 2;  // [4096][2048]
  ushort* qkbuf = (ushort*)ws; ws += (size_t)4096 * 4096 * 2;  // [4096][4096]
  ushort* vt    = (ushort*)ws; ws += (size_t)4096 * 2048 * 2;  // [(b,h,d)][2048]
  ushort* aout  = (ushort*)ws; ws += (size_t)4096 * 2048 * 2;  // [4096][2048]

  dim3 tb(32, 8), tg(64, 64);
  k_transpose<<<tg, tb, 0, stream>>>(Wq, WqkvT);
  k_transpose<<<tg, tb, 0, stream>>>(Wk, WqkvT + (size_t)2048 * 2048);
  k_transpose<<<tg, tb, 0, stream>>>(Wv, WqkvT + (size_t)4096 * 2048);
  k_transpose<<<tg, tb, 0, stream>>>(Wo, WoT);

  k_rmsnorm<<<4096, 256, 0, stream>>>(x, rms_w, xn);

  // QKV: M=4096, N=6144, K=2048
  k_gemm<0><<<dim3(48, 32), 256, 0, stream>>>(xn, WqkvT, qkbuf, vt, nullptr, nullptr, 2048);

  // attention: 512 blocks (16 q-blocks x 32 bh), XCD-grouped
  k_attn2<<<512, 256, 0, stream>>>(qkbuf, vt, aout);

  // out = attn @ Wo + x : M=4096, N=2048, K=2048
  k_gemm<1><<<dim3(16, 32), 256, 0, stream>>>(aout, WoT, nullptr, nullptr, out, x, 2048);
}

// Round 3
// 293.252 us; speedup vs baseline: 1.6354x; 1.0297x over previous
//
#include <hip/hip_runtime.h>
#include <math.h>

typedef __attribute__((ext_vector_type(8))) short bf16x8;
typedef __attribute__((ext_vector_type(4))) float f32x4;
typedef __attribute__((ext_vector_type(16))) float f32x16;

#define HID 2048
#define SEQ 2048
#define NH  16
#define DH  128
#define QK_SCALE 0.02209708691207961f  // 1/sqrt(2048)

__device__ __forceinline__ ushort f2bf(float f) {
  union { float f; unsigned u; } v; v.f = f;
  unsigned r = v.u + 0x7fffu + ((v.u >> 16) & 1u);
  return (ushort)(r >> 16);
}

// async global->LDS, 16B per lane. lds ptr must be wave-uniform; HW adds lane*16.
__device__ __forceinline__ void gload16(const ushort* g, ushort* l) {
  __builtin_amdgcn_global_load_lds((const __attribute__((address_space(1))) void*)g,
                                   (__attribute__((address_space(3))) void*)l,
                                   16, 0, 0);
}

// ---------- transpose fp32 [2048][2048] -> bf16 [2048][2048] (Wt[n][k] = W[k][n]) ----------
__global__ __launch_bounds__(256) void k_transpose(const float* __restrict__ W,
                                                   ushort* __restrict__ Wt) {
  __shared__ float t[32][33];
  int n0 = blockIdx.x * 32, k0 = blockIdx.y * 32;
  int tx = threadIdx.x, ty = threadIdx.y;
  for (int i = ty; i < 32; i += 8)
    t[i][tx] = W[(size_t)(k0 + i) * HID + n0 + tx];
  __syncthreads();
  for (int i = ty; i < 32; i += 8)
    Wt[(size_t)(n0 + i) * HID + k0 + tx] = f2bf(t[tx][i]);
}

// ---------- RMSNorm: x fp32 [4096][2048] -> xn bf16 ----------
__global__ __launch_bounds__(256) void k_rmsnorm(const float* __restrict__ x,
                                                 const float* __restrict__ w,
                                                 ushort* __restrict__ xn) {
  int row = blockIdx.x;
  const float* xr = x + (size_t)row * HID;
  int base = threadIdx.x * 8;
  float4 a = *(const float4*)(xr + base);
  float4 c = *(const float4*)(xr + base + 4);
  float ss = a.x*a.x + a.y*a.y + a.z*a.z + a.w*a.w
           + c.x*c.x + c.y*c.y + c.z*c.z + c.w*c.w;
  #pragma unroll
  for (int off = 32; off > 0; off >>= 1) ss += __shfl_xor(ss, off);
  __shared__ float red[4];
  if ((threadIdx.x & 63) == 0) red[threadIdx.x >> 6] = ss;
  __syncthreads();
  float tot = red[0] + red[1] + red[2] + red[3];
  float sc = rsqrtf(tot * (1.0f / HID) + 1e-5f);
  float4 wa = *(const float4*)(w + base);
  float4 wc = *(const float4*)(w + base + 4);
  ushort h[8];
  h[0] = f2bf(a.x * sc * wa.x); h[1] = f2bf(a.y * sc * wa.y);
  h[2] = f2bf(a.z * sc * wa.z); h[3] = f2bf(a.w * sc * wa.w);
  h[4] = f2bf(c.x * sc * wc.x); h[5] = f2bf(c.y * sc * wc.y);
  h[6] = f2bf(c.z * sc * wc.z); h[7] = f2bf(c.w * sc * wc.w);
  int4 pk;
  pk.x = h[0] | ((int)h[1] << 16);
  pk.y = h[2] | ((int)h[3] << 16);
  pk.z = h[4] | ((int)h[5] << 16);
  pk.w = h[6] | ((int)h[7] << 16);
  *(int4*)&xn[(size_t)row * HID + base] = pk;
}

// ---------- GEMM v2: ring-4 counted-vmcnt pipeline ----------
// C[M][N] = A[M][K](bf16) * Bt[N][K](bf16)^T.  BM=256, BN=128, 8 waves (4Mx2N,
// per-wave 64x64, acc[4][4]).  LDS = 4 chunks x (A 256x32 + B 128x32) = 96KB.
// Slice s (k=32) computed from chunk s&3 while s+1,s+2 in flight and s+3 issues:
// entry wait vmcnt(6) (= 3 loads/slice x 2 slices), never 0 in main loop (T4).
// Swizzle: 16B chunk cp = ck ^ ((row>>1)&3) -> 8 distinct slots per 8-lane group.
// MODE 0: qkv (N=6144): col<4096 -> bf16 qk; col>=4096 (V) -> transposed vt store.
// MODE 1: out-proj (N=2048): fp32 + residual.
template <int MODE>
__global__ __launch_bounds__(512, 2) void k_gemm2(const ushort* __restrict__ A,
                                                  const ushort* __restrict__ Bt,
                                                  ushort* __restrict__ obf,
                                                  ushort* __restrict__ vt,
                                                  float* __restrict__ ofl,
                                                  const float* __restrict__ resid) {
  constexpr int K = 2048, NS = 64;                  // 64 k32-slices
  constexpr int NBN = (MODE == 0) ? 48 : 16;        // blocks along N
  constexpr int QX = ((MODE == 0) ? 768 : 256) / 8; // per-XCD chunk
  __shared__ ushort lds[4][12288];                  // chunk: A[256][32] + B[128][32]
  const int tid = threadIdx.x;
  const int lane = tid & 63, w = tid >> 6;
  const int wm = w >> 1, wn = w & 1;
  const int g = lane >> 4, l15 = lane & 15;
  const int swz = (blockIdx.x & 7) * QX + (blockIdx.x >> 3);
  const int bm = swz / NBN, bn = swz % NBN;

  f32x4 acc[4][4];
  #pragma unroll
  for (int i = 0; i < 4; ++i)
    #pragma unroll
    for (int j = 0; j < 4; ++j) acc[i][j] = f32x4{0.f, 0.f, 0.f, 0.f};

  auto STAGE = [&](int s) {
    const int ch = s & 3, k0 = s * 32;
    #pragma unroll
    for (int c = 0; c < 2; ++c) {                   // A: 2 x 8KB
      int idx = c * 512 + tid;
      int r = idx >> 2, cp = idx & 3;
      int ck = cp ^ ((r >> 1) & 3);
      gload16(&A[(size_t)(bm * 256 + r) * K + k0 + ck * 8],
              &lds[ch][(c * 8 + w) * 512]);
    }
    {                                                // B: 1 x 8KB
      int r = tid >> 2, cp = tid & 3;
      int ck = cp ^ ((r >> 1) & 3);
      gload16(&Bt[(size_t)(bn * 128 + r) * K + k0 + ck * 8],
              &lds[ch][8192 + w * 512]);
    }
  };

  auto COMPUTE = [&](int s) {
    const ushort* La = lds[s & 3];
    const ushort* Lb = La + 8192;
    bf16x8 aF[4], bF[4];
    #pragma unroll
    for (int i = 0; i < 4; ++i) {
      int row = wm * 64 + i * 16 + l15;
      int cp = g ^ ((row >> 1) & 3);
      aF[i] = *(const bf16x8*)&La[row * 32 + cp * 8];
    }
    #pragma unroll
    for (int j = 0; j < 4; ++j) {
      int row = wn * 64 + j * 16 + l15;
      int cp = g ^ ((row >> 1) & 3);
      bF[j] = *(const bf16x8*)&Lb[row * 32 + cp * 8];
    }
    __builtin_amdgcn_s_setprio(1);
    #pragma unroll
    for (int i = 0; i < 4; ++i)
      #pragma unroll
      for (int j = 0; j < 4; ++j)
        acc[i][j] = __builtin_amdgcn_mfma_f32_16x16x32_bf16(aF[i], bF[j], acc[i][j], 0, 0, 0);
    __builtin_amdgcn_s_setprio(0);
  };

  STAGE(0); STAGE(1); STAGE(2);                     // 9 loads in flight
  #pragma unroll 1
  for (int s = 0; s <= NS - 4; ++s) {
    asm volatile("s_waitcnt vmcnt(6)" ::: "memory");  // drain slice s's 3 loads
    __builtin_amdgcn_s_barrier();
    __builtin_amdgcn_sched_barrier(0);
    STAGE(s + 3);                                     // into chunk freed by slice s-1
    COMPUTE(s);
  }
  asm volatile("s_waitcnt vmcnt(6)" ::: "memory");
  __builtin_amdgcn_s_barrier();
  __builtin_amdgcn_sched_barrier(0);
  COMPUTE(NS - 3);
  asm volatile("s_waitcnt vmcnt(3)" ::: "memory");
  __builtin_amdgcn_s_barrier();
  __builtin_amdgcn_sched_barrier(0);
  COMPUTE(NS - 2);
  asm volatile("s_waitcnt vmcnt(0)" ::: "memory");
  __builtin_amdgcn_s_barrier();
  __builtin_amdgcn_sched_barrier(0);
  COMPUTE(NS - 1);

  // C/D layout: col = lane&15, row = (lane>>4)*4 + r
  int rbase = bm * 256 + wm * 64 + g * 4;
  int cbase = bn * 128 + wn * 64 + l15;
  #pragma unroll
  for (int i = 0; i < 4; ++i) {
    #pragma unroll
    for (int j = 0; j < 4; ++j) {
      int col = cbase + j * 16;
      #pragma unroll
      for (int r = 0; r < 4; ++r) {
        int row = rbase + i * 16 + r;
        float v = acc[i][j][r];
        if (MODE == 0) {
          ushort hv = f2bf(v);
          if (col < 4096) {
            obf[(size_t)row * 4096 + col] = hv;
          } else {
            int nv = col - 4096;
            int h = nv >> 7, d = nv & 127;
            int b = row >> 11, s = row & 2047;
            vt[(size_t)((b * NH + h) * DH + d) * SEQ + s] = hv;
          }
        } else {
          ofl[(size_t)row * HID + col] = v + resid[(size_t)row * HID + col];
        }
      }
    }
  }
}

// ---------- flash attention v2: 4 waves x QBLK=32, KVBLK=64, 32x32x16 MFMA ----------
__global__ __launch_bounds__(256, 2) void k_attn2(const ushort* __restrict__ qk,
                                                  const ushort* __restrict__ vt,
                                                  ushort* __restrict__ aout) {
  __shared__ ushort sK[64 * 128];
  __shared__ ushort sV[128 * 64];
  const int tid = threadIdx.x;
  const int lane = tid & 63, w = tid >> 6;
  const int h2 = lane >> 5;          // half of wave
  const int l31 = lane & 31;
  const int bid = blockIdx.x;
  const int t = bid >> 3;
  const int bh = (bid & 7) + 8 * (t >> 4);
  const int qblk = 15 - (t & 15);
  const int b = bh >> 4, hh = bh & 15;
  const int q0w = qblk * 128 + w * 32;   // this wave's 32 q rows

  bf16x8 qf[8];
  {
    const ushort* qbase = qk + (size_t)(b * SEQ + q0w + l31) * 4096 + hh * DH;
    #pragma unroll
    for (int kk = 0; kk < 8; ++kk) qf[kk] = *(const bf16x8*)&qbase[kk * 16 + h2 * 8];
  }

  f32x16 accO[4];
  #pragma unroll
  for (int i = 0; i < 4; ++i)
    #pragma unroll
    for (int r = 0; r < 16; ++r) accO[i][r] = 0.f;
  float m_r = -1e30f, l_r = 0.f;

  const int ntile = 2 * qblk + 2;
  for (int tt = 0; tt < ntile; ++tt) {
    const int t0 = tt * 64;
    #pragma unroll
    for (int c = 0; c < 4; ++c) {
      int id = (w * 4 + c) * 64 + lane;
      int kr = id >> 4, ck = id & 15;   // sK: 256B rows, 16 chunks
      gload16(qk + (size_t)(b * SEQ + t0 + kr) * 4096 + 2048 + hh * DH + ((ck ^ (kr & 7)) * 8),
              ((ushort*)sK) + (size_t)(w * 4 + c) * 512);
      int dr = id >> 3, cv = id & 7;    // sV: 128B rows, 8 chunks
      gload16(vt + (size_t)(bh * DH + dr) * SEQ + t0 + ((cv ^ (dr & 7)) * 8),
              ((ushort*)sV) + (size_t)(w * 4 + c) * 512);
    }
    __syncthreads();

    if (t0 <= q0w + 31) {
      f32x16 accS[2];
      #pragma unroll
      for (int i = 0; i < 2; ++i)
        #pragma unroll
        for (int r = 0; r < 16; ++r) accS[i][r] = 0.f;
      #pragma unroll
      for (int kt = 0; kt < 2; ++kt) {
        const int row = kt * 32 + l31;
        #pragma unroll
        for (int kk = 0; kk < 8; ++kk) {
          const int cp = (kk * 2 + h2) ^ (lane & 7);
          bf16x8 kf = *(const bf16x8*)&sK[row * 128 + cp * 8];
          accS[kt] = __builtin_amdgcn_mfma_f32_32x32x16_bf16(kf, qf[kk], accS[kt], 0, 0, 0);
        }
      }
      const int qa = q0w + l31;
      float pmax = -INFINITY;
      if (t0 + 63 <= q0w) {
        #pragma unroll
        for (int kt = 0; kt < 2; ++kt)
          #pragma unroll
          for (int r = 0; r < 16; ++r) {
            float s = accS[kt][r] * QK_SCALE;
            accS[kt][r] = s;
            pmax = fmaxf(pmax, s);
          }
      } else {
        #pragma unroll
        for (int kt = 0; kt < 2; ++kt)
          #pragma unroll
          for (int r = 0; r < 16; ++r) {
            int ka = t0 + kt * 32 + (r & 3) + 8 * (r >> 2) + 4 * h2;
            float s = (ka <= qa) ? accS[kt][r] * QK_SCALE : -INFINITY;
            accS[kt][r] = s;
            pmax = fmaxf(pmax, s);
          }
      }
      pmax = fmaxf(pmax, __shfl_xor(pmax, 32));
      if (__any(pmax > m_r + 8.f)) {
        float mn = fmaxf(m_r, pmax);
        float al = __expf(m_r - mn);
        m_r = mn;
        l_r *= al;
        #pragma unroll
        for (int r = 0; r < 16; ++r) {
          float ar = __shfl(al, (r & 3) + 8 * (r >> 2) + 4 * h2);
          #pragma unroll
          for (int ds = 0; ds < 4; ++ds) accO[ds][r] *= ar;
        }
      }
      float rs = 0.f;
      #pragma unroll
      for (int kt = 0; kt < 2; ++kt)
        #pragma unroll
        for (int r = 0; r < 16; ++r) {
          float p = __expf(accS[kt][r] - m_r);
          rs += p;
          accS[kt][r] = p;
        }
      rs += __shfl_xor(rs, 32);
      l_r += rs;
      uint W[2][4][2];
      #pragma unroll
      for (int kt = 0; kt < 2; ++kt)
        #pragma unroll
        for (int bq = 0; bq < 4; ++bq)
          #pragma unroll
          for (int w2 = 0; w2 < 2; ++w2) {
            uint u0 = __float_as_uint(accS[kt][bq * 4 + w2 * 2]);
            uint u1 = __float_as_uint(accS[kt][bq * 4 + w2 * 2 + 1]);
            W[kt][bq][w2] = (u0 >> 16) | (u1 & 0xffff0000u);
          }
      #pragma unroll
      for (int kc = 0; kc < 4; ++kc) {
        const int kt = kc >> 1, pq = kc & 1;
        uint X0 = W[kt][2 * pq][0],     X1 = W[kt][2 * pq][1];
        uint Y0 = W[kt][2 * pq + 1][0], Y1 = W[kt][2 * pq + 1][1];
        uint sx0 = (uint)__shfl_xor((int)X0, 32);
        uint sx1 = (uint)__shfl_xor((int)X1, 32);
        uint sy0 = (uint)__shfl_xor((int)Y0, 32);
        uint sy1 = (uint)__shfl_xor((int)Y1, 32);
        union { uint u[4]; bf16x8 v; } pu;
        pu.u[0] = h2 ? sy0 : X0;
        pu.u[1] = h2 ? sy1 : X1;
        pu.u[2] = h2 ? Y0 : sx0;
        pu.u[3] = h2 ? Y1 : sx1;
        #pragma unroll
        for (int ds = 0; ds < 4; ++ds) {
          const int dr = ds * 32 + l31;
          const int cp = (kc * 2 + h2) ^ (lane & 7);
          bf16x8 vf = *(const bf16x8*)&sV[dr * 64 + cp * 8];
          accO[ds] = __builtin_amdgcn_mfma_f32_32x32x16_bf16(pu.v, vf, accO[ds], 0, 0, 0);
        }
      }
    }
    __syncthreads();
  }

  float linv = 1.f / l_r;
  #pragma unroll
  for (int r = 0; r < 16; ++r) {
    int qrel = (r & 3) + 8 * (r >> 2) + 4 * h2;
    float li = __shfl(linv, qrel);
    #pragma unroll
    for (int ds = 0; ds < 4; ++ds) {
      aout[(size_t)(b * SEQ + q0w + qrel) * HID + hh * DH + ds * 32 + l31] =
          f2bf(accO[ds][r] * li);
    }
  }
}

extern "C" void kernel_launch(void* const* d_in, const int* in_sizes, int n_in,
                              void* d_out, int out_size, void* d_ws, size_t ws_size,
                              hipStream_t stream) {
  const float* x     = (const float*)d_in[0];
  const float* rms_w = (const float*)d_in[1];
  const float* Wq    = (const float*)d_in[2];
  const float* Wk    = (const float*)d_in[3];
  const float* Wv    = (const float*)d_in[4];
  const float* Wo    = (const float*)d_in[5];
  float* out = (float*)d_out;

  char* ws = (char*)d_ws;
  ushort* WqkvT = (ushort*)ws; ws += (size_t)6144 * 2048 * 2;  // [6144][2048]
  ushort* WoT   = (ushort*)ws; ws += (size_t)2048 * 2048 * 2;  // [2048][2048]
  ushort* xn    = (ushort*)ws; ws += (size_t)4096 * 2048 * 2;  // [4096][2048]
  ushort* qkbuf = (ushort*)ws; ws += (size_t)4096 * 4096 * 2;  // [4096][4096]
  ushort* vt    = (ushort*)ws; ws += (size_t)4096 * 2048 * 2;  // [(b,h,d)][2048]
  ushort* aout  = (ushort*)ws; ws += (size_t)4096 * 2048 * 2;  // [4096][2048]

  dim3 tb(32, 8), tg(64, 64);
  k_transpose<<<tg, tb, 0, stream>>>(Wq, WqkvT);
  k_transpose<<<tg, tb, 0, stream>>>(Wk, WqkvT + (size_t)2048 * 2048);
  k_transpose<<<tg, tb, 0, stream>>>(Wv, WqkvT + (size_t)4096 * 2048);
  k_transpose<<<tg, tb, 0, stream>>>(Wo, WoT);

  k_rmsnorm<<<4096, 256, 0, stream>>>(x, rms_w, xn);

  // QKV: M=4096, N=6144, K=2048 -> 768 blocks (3 full CU rounds)
  k_gemm2<0><<<768, 512, 0, stream>>>(xn, WqkvT, qkbuf, vt, nullptr, nullptr);

  // attention: 512 blocks (16 q-blocks x 32 bh), XCD-grouped
  k_attn2<<<512, 256, 0, stream>>>(qkbuf, vt, aout);

  // out = attn @ Wo + x : M=4096, N=2048, K=2048 -> 256 blocks (1 round)
  k_gemm2<1><<<256, 512, 0, stream>>>(aout, WoT, nullptr, nullptr, out, x);
}